// Round 6
// baseline (1648.872 us; speedup 1.0000x reference)
//
#include <hip/hip_runtime.h>

// GCN: 3x (linear -> aggregate_by_dst(CSR) -> bias+act), atomic-free float path.
// N=100000, E=1600000, IN=128, HID=OUT=64.
// R5: src-tiled persistent aggregation (8 passes, L2-resident window),
//     register accumulators, LDS-staged adjacency; nt store in k_fill.

#define FOUT 64
#define SCAN_T 256
#define SCAN_ELEMS 1024
#define NPW 25          // nodes per wave (4 waves/block -> 100 nodes/block)
#define NPB 100         // nodes per block
#define AGG_CAP 8192    // LDS-staged csr entries per block (mean ~1600, +160 sigma)
#define NPASS 8

// ---------------- dense linear ----------------
// Register-tiled: 256 thr = 4 waves, 64 rows/block, full K staged.
// Thread owns 4 features x 4 rows; W and x both read as ds_read_b128.
template<int K>
__global__ __launch_bounds__(256) void k_linear(
    const float* __restrict__ in, const float* __restrict__ W,
    float* __restrict__ out, int n) {
    constexpr int XSTR = (K == 128) ? 132 : 68;
    __shared__ float4 sW4[K * 16];
    __shared__ float xs[64 * XSTR];

    const int t = threadIdx.x;
    const int base = blockIdx.x * 64;

    const float4* W4 = (const float4*)W;
#pragma unroll
    for (int i = 0; i < K * 16 / 256; ++i) sW4[t + i * 256] = W4[t + i * 256];

    constexpr int CPR = K / 4;
#pragma unroll
    for (int i = 0; i < 64 * CPR / 256; ++i) {
        int flat = t + i * 256;
        int row = flat / CPR;
        int c4 = flat % CPR;
        int rg = base + row;
        if (rg < n) {
            float4 v = *(const float4*)(in + (size_t)rg * K + c4 * 4);
            *(float4*)&xs[row * XSTR + c4 * 4] = v;
        }
    }
    __syncthreads();

    const int fq = t & 15;
    const int slot = (t >> 4) & 3;
    const int wave = t >> 6;
    const int r0 = wave * 16 + slot * 4;

    float4 acc[4];
#pragma unroll
    for (int i = 0; i < 4; ++i) acc[i] = make_float4(0.f, 0.f, 0.f, 0.f);

#pragma unroll 8
    for (int k = 0; k < K; k += 4) {
        float4 w0 = sW4[(k + 0) * 16 + fq];
        float4 w1 = sW4[(k + 1) * 16 + fq];
        float4 w2 = sW4[(k + 2) * 16 + fq];
        float4 w3 = sW4[(k + 3) * 16 + fq];
#pragma unroll
        for (int i = 0; i < 4; ++i) {
            float4 xv = *(const float4*)&xs[(r0 + i) * XSTR + k];
            acc[i].x = fmaf(xv.x, w0.x, acc[i].x);
            acc[i].y = fmaf(xv.x, w0.y, acc[i].y);
            acc[i].z = fmaf(xv.x, w0.z, acc[i].z);
            acc[i].w = fmaf(xv.x, w0.w, acc[i].w);
            acc[i].x = fmaf(xv.y, w1.x, acc[i].x);
            acc[i].y = fmaf(xv.y, w1.y, acc[i].y);
            acc[i].z = fmaf(xv.y, w1.z, acc[i].z);
            acc[i].w = fmaf(xv.y, w1.w, acc[i].w);
            acc[i].x = fmaf(xv.z, w2.x, acc[i].x);
            acc[i].y = fmaf(xv.z, w2.y, acc[i].y);
            acc[i].z = fmaf(xv.z, w2.z, acc[i].z);
            acc[i].w = fmaf(xv.z, w2.w, acc[i].w);
            acc[i].x = fmaf(xv.w, w3.x, acc[i].x);
            acc[i].y = fmaf(xv.w, w3.y, acc[i].y);
            acc[i].z = fmaf(xv.w, w3.z, acc[i].z);
            acc[i].w = fmaf(xv.w, w3.w, acc[i].w);
        }
    }

#pragma unroll
    for (int i = 0; i < 4; ++i) {
        int rg = base + r0 + i;
        if (rg < n) *(float4*)(out + (size_t)rg * FOUT + fq * 4) = acc[i];
    }
}

// ---------------- CSR build ----------------
__global__ __launch_bounds__(256) void k_hist(
    const int* __restrict__ dst, int* __restrict__ cnt, int ne) {
    const int stride = gridDim.x * blockDim.x;
    for (int i = blockIdx.x * blockDim.x + threadIdx.x; i < ne; i += stride)
        atomicAdd(&cnt[dst[i]], 1);
}

__global__ __launch_bounds__(SCAN_T) void k_scan1(
    const int* __restrict__ cnt, int* __restrict__ ex,
    int* __restrict__ partials, int n) {
    __shared__ int s[SCAN_T];
    const int base = blockIdx.x * SCAN_ELEMS;
    int vals[4];
    int sum = 0;
#pragma unroll
    for (int j = 0; j < 4; ++j) {
        int idx = base + threadIdx.x * 4 + j;
        int v = (idx < n) ? cnt[idx] : 0;
        vals[j] = sum;
        sum += v;
    }
    s[threadIdx.x] = sum;
    __syncthreads();
    for (int ofs = 1; ofs < SCAN_T; ofs <<= 1) {
        int v = (threadIdx.x >= ofs) ? s[threadIdx.x - ofs] : 0;
        __syncthreads();
        s[threadIdx.x] += v;
        __syncthreads();
    }
    const int texc = s[threadIdx.x] - sum;
#pragma unroll
    for (int j = 0; j < 4; ++j) {
        int idx = base + threadIdx.x * 4 + j;
        if (idx < n) ex[idx] = texc + vals[j];
    }
    if (threadIdx.x == SCAN_T - 1) partials[blockIdx.x] = s[threadIdx.x];
}

__global__ __launch_bounds__(SCAN_T) void k_scan2(
    const int* __restrict__ partials, int* __restrict__ partial_ofs, int nb) {
    __shared__ int s[SCAN_T];
    int v = (threadIdx.x < nb) ? partials[threadIdx.x] : 0;
    s[threadIdx.x] = v;
    __syncthreads();
    for (int ofs = 1; ofs < SCAN_T; ofs <<= 1) {
        int t = (threadIdx.x >= ofs) ? s[threadIdx.x - ofs] : 0;
        __syncthreads();
        s[threadIdx.x] += t;
        __syncthreads();
    }
    if (threadIdx.x < nb) partial_ofs[threadIdx.x] = s[threadIdx.x] - v;
}

__global__ __launch_bounds__(256) void k_scan3(
    int* __restrict__ row_ofs, const int* __restrict__ partial_ofs,
    int* __restrict__ cursor, int n, int ne) {
    const int i = blockIdx.x * blockDim.x + threadIdx.x;
    if (i < n) {
        int v = row_ofs[i] + partial_ofs[i >> 10];
        row_ofs[i] = v;
        cursor[i] = v;
    }
    if (i == 0) row_ofs[n] = ne;
}

__global__ __launch_bounds__(256) void k_fill(
    const int* __restrict__ src, const int* __restrict__ dst,
    int* __restrict__ cursor, int* __restrict__ csr_src, int ne) {
    const int stride = gridDim.x * blockDim.x;
    for (int i = blockIdx.x * blockDim.x + threadIdx.x; i < ne; i += stride) {
        int d = dst[i];
        int p = atomicAdd(&cursor[d], 1);
        __builtin_nontemporal_store(src[i], &csr_src[p]);
    }
}

// ---------------- src-tiled persistent aggregation ----------------
// 1000 co-resident blocks (4/CU). Wave owns NPW nodes (acc in VGPRs,
// statically unrolled). NPASS passes over src tiles (12.5k nodes = 3.2MB,
// L2-resident window); per pass the wave rescans its LDS-staged adjacency
// and gathers only in-tile edges (wave-uniform scalar test via
// readfirstlane). Bias + activation fused. ACT: 0 = ReLU, 1 = sigmoid.
template<int ACT>
__global__ __launch_bounds__(256, 4) void k_agg_tiled(
    const int* __restrict__ row_ofs, const int* __restrict__ csr_src,
    const float* __restrict__ msg, const float* __restrict__ bias,
    float* __restrict__ out, int n, int ntile) {
    __shared__ int sRow[NPB + 1];
    __shared__ int sIdx[AGG_CAP];

    const int t = threadIdx.x;
    const int lane = t & 63;
    const int wid = t >> 6;
    const int nodeB = blockIdx.x * NPB;
    const int nB = min(NPB, n - nodeB);

    for (int i = t; i <= nB; i += 256) sRow[i] = row_ofs[nodeB + i];
    __syncthreads();
    const int sBeg = sRow[0];
    const int extent = sRow[nB] - sBeg;
    const bool useLds = (extent <= AGG_CAP);
    if (useLds) {
        for (int i = t; i < extent; i += 256) sIdx[i] = csr_src[sBeg + i];
    }
    __syncthreads();

    const int node0 = nodeB + wid * NPW;
    float acc[NPW];
#pragma unroll
    for (int s = 0; s < NPW; ++s) acc[s] = 0.f;

    for (int p = 0; p < NPASS; ++p) {
        const int lo = p * ntile;
        const int hi = lo + ntile;
#pragma unroll
        for (int s = 0; s < NPW; ++s) {
            const int node = node0 + s;
            if (node < n) {
                const int jb = sRow[wid * NPW + s];
                const int je = sRow[wid * NPW + s + 1];
                float a = acc[s];
                if (useLds) {
                    for (int j = jb; j < je; ++j) {
                        int sv = __builtin_amdgcn_readfirstlane(sIdx[j - sBeg]);
                        if (sv >= lo && sv < hi)
                            a += msg[(size_t)sv * FOUT + lane];
                    }
                } else {
                    for (int j = jb; j < je; ++j) {
                        int sv = __builtin_amdgcn_readfirstlane(csr_src[j]);
                        if (sv >= lo && sv < hi)
                            a += msg[(size_t)sv * FOUT + lane];
                    }
                }
                acc[s] = a;
            }
        }
    }

#pragma unroll
    for (int s = 0; s < NPW; ++s) {
        const int node = node0 + s;
        if (node < n) {
            float v = acc[s] + bias[lane];
            out[(size_t)node * FOUT + lane] =
                (ACT == 0) ? fmaxf(v, 0.f) : 1.f / (1.f + __expf(-v));
        }
    }
}

extern "C" void kernel_launch(void* const* d_in, const int* in_sizes, int n_in,
                              void* d_out, int out_size, void* d_ws, size_t ws_size,
                              hipStream_t stream) {
    const float* x  = (const float*)d_in[0];
    const int*   ei = (const int*)d_in[1];
    const float* W1 = (const float*)d_in[2];
    const float* b1 = (const float*)d_in[3];
    const float* W2 = (const float*)d_in[4];
    const float* b2 = (const float*)d_in[5];
    const float* W3 = (const float*)d_in[6];
    const float* b3 = (const float*)d_in[7];
    float* out = (float*)d_out;

    const int n  = in_sizes[0] / 128;   // 100000
    const int ne = in_sizes[1] / 2;     // 1600000
    const int* src = ei;
    const int* dst = ei + ne;

    const size_t feat_elems = (size_t)n * FOUT;

    float* A        = (float*)d_ws;
    float* B        = A + feat_elems;
    int*   cnt      = (int*)(B + feat_elems);
    int*   row_ofs  = cnt + n;
    int*   cursor   = row_ofs + n + 1;
    int*   partials = cursor + n;
    int*   partial_ofs = partials + 128;
    int*   csr_src  = partial_ofs + 128;

    const int nScanBlocks = (n + SCAN_ELEMS - 1) / SCAN_ELEMS;
    const int gLin = (n + 63) / 64;
    const int gAgg = (n + NPB - 1) / NPB;       // 1000
    const int ntile = (n + NPASS - 1) / NPASS;  // 12500

    // ---- CSR build ----
    hipMemsetAsync(cnt, 0, (size_t)n * sizeof(int), stream);
    k_hist<<<2048, 256, 0, stream>>>(dst, cnt, ne);
    k_scan1<<<nScanBlocks, SCAN_T, 0, stream>>>(cnt, row_ofs, partials, n);
    k_scan2<<<1, SCAN_T, 0, stream>>>(partials, partial_ofs, nScanBlocks);
    k_scan3<<<(n + 255) / 256, 256, 0, stream>>>(row_ofs, partial_ofs, cursor, n, ne);
    k_fill<<<2048, 256, 0, stream>>>(src, dst, cursor, csr_src, ne);

    // ---- Layer 1 ----
    k_linear<128><<<gLin, 256, 0, stream>>>(x, W1, A, n);
    k_agg_tiled<0><<<gAgg, 256, 0, stream>>>(row_ofs, csr_src, A, b1, B, n, ntile);
    // ---- Layer 2 ----
    k_linear<64><<<gLin, 256, 0, stream>>>(B, W2, A, n);
    k_agg_tiled<0><<<gAgg, 256, 0, stream>>>(row_ofs, csr_src, A, b2, B, n, ntile);
    // ---- Layer 3 ----
    k_linear<64><<<gLin, 256, 0, stream>>>(B, W3, A, n);
    k_agg_tiled<1><<<gAgg, 256, 0, stream>>>(row_ofs, csr_src, A, b3, out, n, ntile);
}